// Round 5
// baseline (218.564 us; speedup 1.0000x reference)
//
#include <hip/hip_runtime.h>
#include <stdint.h>

// SparseAttention MI355X bf16-MFMA pipeline. Output f32.
// R16: qkv_gemm rewritten as 256x256 8-wave pipelined GEMM (BK=64):
//  - 1 barrier per K-step: issue next-tile global_load_lds FIRST, then
//    ds_read+MFMA (compute hides L2 latency), then one __syncthreads whose
//    implicit vmcnt-drain is already satisfied. (m97's 2-barrier structure
//    exposes full load latency to all waves each step — documented ceiling.)
//  - MFMA:ds_read 64:24 per K-step (2x density of the 128x128 loop).
//  - LDS [256][64] u16 rows (128B), 16B-slot XOR swizzle slot^=(row&7):
//    linear gload_lds dest + pre-swizzled GLOBAL source (both-sides rule);
//    same scheme verified 0-conflict in attn (R13/R15).
//  - grid 288=8x36 chunked XCD swizzle; launch_bounds(512,2) (256-VGPR
//    budget for acc[8][4]+frags; spill alarm = WRITE_SIZE).
// proj/prep/vprep/attn unchanged from R15 (attn 52.4us, VGPR 64, no spill,
// BANK_CONFLICT 0).
// MFMA 16x16x32 bf16 layouts (HW-verified): A[m=lane&15][k=quad*8+j],
// B[k=quad*8+j][n=lane&15], C/D col=lane&15 row=quad*4+reg.

#define NH 12
#define SQ 2048

typedef __bf16 bf16x8 __attribute__((ext_vector_type(8)));
typedef float f32x4 __attribute__((ext_vector_type(4)));

#define GLOAD_LDS16(g, l)                                                      \
  __builtin_amdgcn_global_load_lds(                                            \
      (__attribute__((address_space(1))) void*)(g),                            \
      (__attribute__((address_space(3))) void*)(l), 16, 0, 0)

__device__ __forceinline__ unsigned short bfbits(float f) {
  __bf16 h = (__bf16)f;
  return *(unsigned short*)&h;
}

// ---------------- prep: x->bf16 + both weight transposes (1 kernel) --------
__global__ __launch_bounds__(256) void prep(
    const float* __restrict__ x, unsigned short* __restrict__ xb,
    const float* __restrict__ w_attn, unsigned short* __restrict__ wattnT,
    const float* __restrict__ w_proj, unsigned short* __restrict__ wprojT) {
  const int bid = blockIdx.x, t = threadIdx.x;
  if (bid < 512) {                 // convert x: 8192*768 floats
    const int n4 = 8192 * 768 / 4;
    for (int i = bid * 256 + t; i < n4; i += 512 * 256) {
      float4 v = ((const float4*)x)[i];
      ((ushort4*)xb)[i] = make_ushort4(bfbits(v.x), bfbits(v.y), bfbits(v.z), bfbits(v.w));
    }
    return;
  }
  __shared__ float tile[32][33];
  const float* in; unsigned short* out; int K, N, tl;
  if (bid < 512 + 72 * 24) { in = w_attn; out = wattnT; K = 768; N = 2304; tl = bid - 512; }
  else                     { in = w_proj; out = wprojT; K = 768; N = 768;  tl = bid - 512 - 72 * 24; }
  const int tpr = N / 32;
  const int n0 = (tl % tpr) * 32, k0 = (tl / tpr) * 32;
  const int tx = t & 31, ty = t >> 5;
  for (int r = ty; r < 32; r += 8) tile[r][tx] = in[(size_t)(k0 + r) * N + n0 + tx];
  __syncthreads();
  for (int r = ty; r < 32; r += 8) out[(size_t)(n0 + r) * K + k0 + tx] = bfbits(tile[tx][r]);
}

// ---------------- vprep: V transpose + gcol gather (1 kernel) ----------------
__global__ __launch_bounds__(256) void vprep(const unsigned short* __restrict__ QKV,
                                             unsigned short* __restrict__ Vtb,
                                             unsigned short* __restrict__ Kg,
                                             unsigned short* __restrict__ VgT,
                                             int* __restrict__ gidx) {
  const int id = blockIdx.x, t = threadIdx.x;
  if (id < 1536) {                 // vtrans
    const int bh = id >> 5, b = bh / NH, h = bh % NH;
    const int s0 = (id & 31) * 64;
    __shared__ unsigned short T[64][72];
    const int r = t >> 2, c0 = (t & 3) * 16;
    const size_t src = (size_t)(b * SQ + s0 + r) * 2304 + 1536 + h * 64 + c0;
    *(uint4*)&T[r][c0]     = *(const uint4*)&QKV[src];
    *(uint4*)&T[r][c0 + 8] = *(const uint4*)&QKV[src + 8];
    __syncthreads();
    unsigned short pk[16];
#pragma unroll
    for (int z = 0; z < 16; ++z) pk[z] = T[c0 + z][r];
    size_t dst = (size_t)bh * 131072 + (size_t)r * 2048 + s0 + c0;
    *(uint4*)&Vtb[dst]     = *(uint4*)&pk[0];
    *(uint4*)&Vtb[dst + 8] = *(uint4*)&pk[8];
    return;
  }
  const int g = id - 1536;         // gather: 16 bh * 8 chunks
  const int bh = g >> 3, y = g & 7;
  const int b = bh >> 2, h = 8 + (bh & 3);
  if (g == 0) {
    int c = t;
    gidx[c] = (c < 203) ? (int)((double)c * (2047.0 / 203.0)) : ((c == 203) ? 2047 : -1);
  }
  {  // Kg rows from qkvb K-section
    int c = t, ch = y;
    int col = (c < 203) ? (int)((double)c * (2047.0 / 203.0)) : ((c == 203) ? 2047 : -1);
    uint4 v = {0u, 0u, 0u, 0u};
    if (col >= 0) v = *(const uint4*)&QKV[(size_t)(b * SQ + col) * 2304 + 768 + h * 64 + ch * 8];
    *(uint4*)&Kg[((size_t)bh * 256 + c) * 64 + ch * 8] = v;
  }
  {  // VgT directly from qkvb V-section (transpose gather)
    int d = t >> 2;
    int cb = (t & 3) * 64 + y * 8;
    for (int cc = 0; cc < 8; ++cc) {
      int c = cb + cc;
      int col = (c < 203) ? (int)((double)c * (2047.0 / 203.0)) : ((c == 203) ? 2047 : -1);
      unsigned short v = 0;
      if (col >= 0) v = QKV[(size_t)(b * SQ + col) * 2304 + 1536 + h * 64 + d];
      VgT[((size_t)bh * 64 + d) * 256 + c] = v;
    }
  }
}

// -------- R16: 256x256 8-wave pipelined QKV GEMM (1 barrier / K-step) ------
// LDS per buf: A,B tiles [256][64] u16 (row=128B, 8x16B slots, swz ^=row&7).
// Waves 2M x 4N; per-wave out 128x64 (mrep 8 x nrep 4); 64 MFMA / K-step.
__global__ __launch_bounds__(512, 2) void qkv_gemm256(
    const unsigned short* __restrict__ Xb, const unsigned short* __restrict__ WT,
    const float* __restrict__ bias, unsigned short* __restrict__ Out) {
  __shared__ __attribute__((aligned(16))) unsigned short As[2][256 * 64];
  __shared__ __attribute__((aligned(16))) unsigned short Bs[2][256 * 64];
  const int tid = threadIdx.x, lane = tid & 63, wave = tid >> 6;
  // 288 blocks (32 m x 9 n), 288%8==0: chunked bijective XCD swizzle.
  const int wg = (blockIdx.x & 7) * 36 + (blockIdx.x >> 3);
  const int m0 = (wg / 9) * 256, n0 = (wg % 9) * 256;
  const int ln = lane & 15, quad = lane >> 4;
  const int wm = wave >> 2, wn = wave & 3;
  // staging: thread covers row i*64+srow; linear LDS slot t&7, source slot
  // pre-swizzled so LDS[r][s] holds global slot s^(r&7)  (r&7 == (t>>3)&7).
  const int srow = tid >> 3;
  const int scol = ((tid & 7) ^ (srow & 7)) * 8;   // element offset in 64-col row
  // read-side swizzled slots (u16 offsets): kh half 0 -> slots 0..3, kh1 -> 4..7
  const int ln7 = ln & 7;
  const int sk0 = (quad ^ ln7) * 8;
  const int sk1 = ((quad + 4) ^ ln7) * 8;

  f32x4 acc[8][4];
#pragma unroll
  for (int mi = 0; mi < 8; ++mi)
#pragma unroll
    for (int ni = 0; ni < 4; ++ni) acc[mi][ni] = (f32x4){0.f, 0.f, 0.f, 0.f};

  auto stage = [&](int kt, int buf) {
    const int k0 = kt * 64;
#pragma unroll
    for (int i = 0; i < 4; ++i) {
      GLOAD_LDS16(Xb + (size_t)(m0 + i * 64 + srow) * 768 + k0 + scol,
                  &As[buf][(i * 512 + wave * 64) * 8]);
      GLOAD_LDS16(WT + (size_t)(n0 + i * 64 + srow) * 768 + k0 + scol,
                  &Bs[buf][(i * 512 + wave * 64) * 8]);
    }
  };

  stage(0, 0);
  __syncthreads();
  int cur = 0;
  for (int kt = 0; kt < 12; ++kt) {
    if (kt + 1 < 12) stage(kt + 1, cur ^ 1);   // in flight across compute
#pragma unroll
    for (int kh = 0; kh < 2; ++kh) {
      const int sk = kh ? sk1 : sk0;
      bf16x8 aF[8], bF[4];
#pragma unroll
      for (int mi = 0; mi < 8; ++mi)
        aF[mi] = *(const bf16x8*)&As[cur][(wm * 128 + mi * 16 + ln) * 64 + sk];
#pragma unroll
      for (int ni = 0; ni < 4; ++ni)
        bF[ni] = *(const bf16x8*)&Bs[cur][(wn * 64 + ni * 16 + ln) * 64 + sk];
#pragma unroll
      for (int mi = 0; mi < 8; ++mi)
#pragma unroll
        for (int ni = 0; ni < 4; ++ni)
          acc[mi][ni] = __builtin_amdgcn_mfma_f32_16x16x32_bf16(aF[mi], bF[ni], acc[mi][ni], 0, 0, 0);
    }
    __syncthreads();   // drains stage loads (hidden under MFMA) + frees bufs
    cur ^= 1;
  }

#pragma unroll
  for (int mi = 0; mi < 8; ++mi)
#pragma unroll
    for (int ni = 0; ni < 4; ++ni) {
      int n = n0 + wn * 64 + ni * 16 + ln;
      float bs = bias[n];
#pragma unroll
      for (int rg = 0; rg < 4; ++rg) {
        int m = m0 + wm * 128 + mi * 16 + quad * 4 + rg;
        Out[(size_t)m * 2304 + n] = bfbits(acc[mi][ni][rg] + bs);
      }
    }
}

// ------ GEMM mainloop (BM=BN=128, BK=64 via 2 panels, async LDS DMA) -------
// (kept for proj_gemm)
__device__ __forceinline__ void gemm_mainloop(
    const unsigned short* __restrict__ A, const unsigned short* __restrict__ BT,
    int m0, int n0, int tid,
    unsigned short* As, unsigned short* Bs,
    f32x4 acc[4][4]) {
  const int lane = tid & 63, wave = tid >> 6;
  const int wm = wave >> 1, wn = wave & 1;
  const int ln = lane & 15, quad = lane >> 4;
  const int arow = wave * 16 + (lane >> 2);   // +p*64 : staged row
  const int acol = (lane & 3) * 8;            // element offset in 32-col panel

#pragma unroll
  for (int mi = 0; mi < 4; ++mi)
#pragma unroll
    for (int ni = 0; ni < 4; ++ni) acc[mi][ni] = (f32x4){0.f, 0.f, 0.f, 0.f};

  for (int kt = 0; kt < 12; ++kt) {
    const int k0 = kt * 64;
    __syncthreads();
#pragma unroll
    for (int p = 0; p < 2; ++p) {
      const int ldso = (p * 64 + wave * 16) * 32;
      GLOAD_LDS16(A  + (size_t)(m0 + p * 64 + arow) * 768 + k0 + acol,       &As[ldso]);
      GLOAD_LDS16(A  + (size_t)(m0 + p * 64 + arow) * 768 + k0 + 32 + acol,  &As[4096 + ldso]);
      GLOAD_LDS16(BT + (size_t)(n0 + p * 64 + arow) * 768 + k0 + acol,       &Bs[ldso]);
      GLOAD_LDS16(BT + (size_t)(n0 + p * 64 + arow) * 768 + k0 + 32 + acol,  &Bs[4096 + ldso]);
    }
    __syncthreads();
#pragma unroll
    for (int kh = 0; kh < 2; ++kh) {
      const int base = kh * 4096;
      bf16x8 aF[4], bF[4];
#pragma unroll
      for (int mi = 0; mi < 4; ++mi)
        aF[mi] = *(const bf16x8*)&As[base + (wm * 64 + mi * 16 + ln) * 32 + quad * 8];
#pragma unroll
      for (int ni = 0; ni < 4; ++ni)
        bF[ni] = *(const bf16x8*)&Bs[base + (wn * 64 + ni * 16 + ln) * 32 + quad * 8];
#pragma unroll
      for (int mi = 0; mi < 4; ++mi)
#pragma unroll
        for (int ni = 0; ni < 4; ++ni)
          acc[mi][ni] = __builtin_amdgcn_mfma_f32_16x16x32_bf16(aF[mi], bF[ni], acc[mi][ni], 0, 0, 0);
    }
  }
}

// ---------------- Proj GEMM: fp32 out (XCD-swizzled 1D grid) ---------------
__global__ __launch_bounds__(256) void proj_gemm(
    const unsigned short* __restrict__ Ab, const unsigned short* __restrict__ WT,
    const float* __restrict__ bias, float* __restrict__ Out) {
  __shared__ __attribute__((aligned(16))) unsigned short As[2 * 128 * 32];
  __shared__ __attribute__((aligned(16))) unsigned short Bs[2 * 128 * 32];
  f32x4 acc[4][4];
  // 384 blocks (64 m x 6 n), 384%8==0.
  const int wg = (blockIdx.x & 7) * 48 + (blockIdx.x >> 3);
  const int m0 = (wg / 6) * 128, n0 = (wg % 6) * 128;
  const int tid = threadIdx.x;
  gemm_mainloop(Ab, WT, m0, n0, tid, As, Bs, acc);
  const int lane = tid & 63, wave = tid >> 6;
  const int wm = wave >> 1, wn = wave & 1, ln = lane & 15, quad = lane >> 4;
#pragma unroll
  for (int mi = 0; mi < 4; ++mi)
#pragma unroll
    for (int ni = 0; ni < 4; ++ni)
#pragma unroll
      for (int rg = 0; rg < 4; ++rg) {
        int m = m0 + wm * 64 + mi * 16 + quad * 4 + rg;
        int n = n0 + wn * 64 + ni * 16 + ln;
        Out[(size_t)m * 768 + n] = acc[mi][ni][rg] + bias[n];
      }
}

// ---------------- Flash attention (R15: swizzled LDS, 128-reg budget) ------
// Virtual tile space per (bh,qb) global row: vt 0..3 = g-tiles, vt>=4 ->
// causal kb=vt-4 (0..qb). T=qb+5 tiles split into ceil(T/8) parts of <=8.
// Grid 2560: [0,1536) global parts (slot==gid), [1536,2560) local (<=5 tiles).
// LDS rows are 64 u16 (128B) with 16B-slot XOR swizzle: slot ^= (row&7).
__global__ __launch_bounds__(256, 4) void attn_kernel(
    const unsigned short* __restrict__ QKV,   // [8192][2304]
    const unsigned short* __restrict__ Vtb,   // [48][64][2048]
    const unsigned short* __restrict__ Kg, const unsigned short* __restrict__ VgT,
    const int* __restrict__ gidx,
    unsigned short* __restrict__ AOut,        // [8192][768]
    unsigned short* __restrict__ Opart,       // [1536][4096] bf16
    float* __restrict__ Lpart) {              // [1536][64]
  __shared__ __attribute__((aligned(16))) unsigned short Ks[64 * 64];
  __shared__ __attribute__((aligned(16))) unsigned short Vs[64 * 64];
  __shared__ __attribute__((aligned(16))) unsigned short Ps[64 * 64];  // wave-private rows

  const int gid = blockIdx.x;
  int b, h, qb, vt0, vt1;
  bool multi = false;
  if (gid < 1536) {
    int bh = gid / 96, rem = gid % 96;
    b = bh >> 2; h = 8 + (bh & 3);
    int part;
    if (rem < 4)       { qb = rem;                               part = 0; }
    else if (rem < 20) { int z = rem - 4;  qb = 4 + (z >> 1);    part = z & 1; }
    else if (rem < 44) { int z = rem - 20; int q = z / 3; qb = 12 + q; part = z - 3 * q; }
    else if (rem < 76) { int z = rem - 44; qb = 20 + (z >> 2);   part = z & 3; }
    else               { int z = rem - 76; int q = z / 5; qb = 28 + q; part = z - 5 * q; }
    vt0 = part * 8;
    vt1 = min(vt0 + 8, qb + 5);
    multi = (qb >= 4);
  } else {
    int lid = gid - 1536;
    int bh = lid >> 5; b = bh >> 3; h = bh & 7; qb = lid & 31;
    vt0 = ((qb > 4) ? qb - 4 : 0) + 4;
    vt1 = qb + 5;
  }
  const int qb0 = qb * 64;
  const bool is_local = (h < 8);
  const int tid = threadIdx.x, lane = tid & 63, wave = tid >> 6;
  const int ln = lane & 15, quad = lane >> 4;
  const int bh48 = b * NH + h;
  const int bhg = (b << 2) | (h & 3);

  const size_t qoff = (size_t)(b * SQ + qb0 + wave * 16 + ln) * 2304 + h * 64;
  bf16x8 qA0 = *(const bf16x8*)&QKV[qoff + quad * 8];
  bf16x8 qA1 = *(const bf16x8*)&QKV[qoff + 32 + quad * 8];

  bf16x8 onesF;
#pragma unroll
  for (int z = 0; z < 8; ++z) onesF[z] = (__bf16)1.0f;

  f32x4 o[4];
  f32x4 ls = (f32x4){0.f, 0.f, 0.f, 0.f};
#pragma unroll
  for (int dt = 0; dt < 4; ++dt) o[dt] = (f32x4){0.f, 0.f, 0.f, 0.f};

  const int irow = qb0 + wave * 16 + quad * 4;  // + rg
  const int iw = qb0 + wave * 16;
  const int sr = tid >> 3, sch = tid & 7;
  // swizzled 16B-slot offsets (u16 units)
  const int ssw = (sch ^ (sr & 7)) * 8;             // staging write slot
  const int s0k = (quad ^ (ln & 7)) * 8;            // frag read slot, cols 0..31
  const int s1k = ((quad + 4) ^ (ln & 7)) * 8;      // frag read slot, cols 32..63
  const int lnh = ln >> 3, ln7 = ln & 7;

  // exp2-folded softmax constants: p = exp2(c*S2 - B2) == exp(c/8 - 8)
  const float S2 = 0.125f * 1.44269504f, B2 = 8.0f * 1.44269504f;

  // T14 prefetch registers: next tile's K/V (16 VGPRs)
  uint4 pk0, pk1, pv0, pv1;
  auto issue_load = [&](int vt) {
    if (vt >= 4) {
      const int kstart = (vt - 4) * 64;
      const size_t ko = (size_t)(b * SQ + kstart + sr) * 2304 + 768 + h * 64 + sch * 8;
      pk0 = *(const uint4*)&QKV[ko];
      pk1 = *(const uint4*)&QKV[ko + (size_t)32 * 2304];
      const size_t vo = (size_t)bh48 * 131072 + (size_t)sr * 2048 + kstart + sch * 8;
      pv0 = *(const uint4*)&Vtb[vo];
      pv1 = *(const uint4*)&Vtb[vo + 32 * 2048];
    } else {
      const int kg0 = vt * 64;
      pk0 = *(const uint4*)&Kg[((size_t)bhg * 256 + kg0 + sr) * 64 + sch * 8];
      pk1 = *(const uint4*)&Kg[((size_t)bhg * 256 + kg0 + 32 + sr) * 64 + sch * 8];
      pv0 = *(const uint4*)&VgT[((size_t)bhg * 64 + sr) * 256 + kg0 + sch * 8];
      pv1 = *(const uint4*)&VgT[((size_t)bhg * 64 + 32 + sr) * 256 + kg0 + sch * 8];
    }
  };
  issue_load(vt0);

  for (int vt = vt0; vt < vt1; ++vt) {
    const bool gph = (vt < 4);
    __syncthreads();  // barrier A: all waves done reading prev Ks/Vs (drains prefetch)
    *(uint4*)&Ks[sr * 64 + ssw]        = pk0;   // (32+sr)&7 == sr&7: same slot
    *(uint4*)&Ks[(32 + sr) * 64 + ssw] = pk1;
    *(uint4*)&Vs[sr * 64 + ssw]        = pv0;
    *(uint4*)&Vs[(32 + sr) * 64 + ssw] = pv1;
    __syncthreads();  // barrier B: staged tile visible
    if (vt + 1 < vt1) issue_load(vt + 1);  // in flight across QK+SM+PV

    const int kstart = (vt - 4) * 64;  // valid when !gph
    const int kg0 = vt * 64;           // valid when gph
    float sc[4][4];
    const bool full = !gph && (kstart + 63 <= iw) && (!is_local || kstart >= iw - 241);
#pragma unroll
    for (int nt = 0; nt < 4; ++nt) {
      bf16x8 kF0 = *(const bf16x8*)&Ks[(nt * 16 + ln) * 64 + s0k];
      bf16x8 kF1 = *(const bf16x8*)&Ks[(nt * 16 + ln) * 64 + s1k];
      f32x4 c = (f32x4){0.f, 0.f, 0.f, 0.f};
      c = __builtin_amdgcn_mfma_f32_16x16x32_bf16(qA0, kF0, c, 0, 0, 0);
      c = __builtin_amdgcn_mfma_f32_16x16x32_bf16(qA1, kF1, c, 0, 0, 0);
      if (full) {
#pragma unroll
        for (int rg = 0; rg < 4; ++rg) sc[nt][rg] = c[rg] * S2 - B2;
      } else if (!gph) {
        int j = kstart + nt * 16 + ln;
#pragma unroll
        for (int rg = 0; rg < 4; ++rg) {
          int i = irow + rg;
          bool ok = is_local ? (j >= i - 256 && j <= i) : (j <= i);
          sc[nt][rg] = ok ? (c[rg] * S2 - B2) : -1e9f;
        }
      } else {
        int jg = gidx[kg0 + nt * 16 + ln];
#pragma unroll
        for (int rg = 0; rg < 4; ++rg) {
          bool ok = jg > (irow + rg);
          sc[nt][rg] = ok ? (c[rg] * S2 - B2) : -1e9f;
        }
      }
    }

    // P in its own buffer: each wave writes+reads only rows wave*16..+15 ->
    // no barrier (same-wave DS ordering), prefetch stays in flight.
    __bf16* P = (__bf16*)Ps;
#pragma unroll
    for (int rg = 0; rg < 4; ++rg) {
      int prow = wave * 16 + quad * 4 + rg;
      int pbase = prow * 64 + ln7;
      int pr7 = prow & 7;
#pragma unroll
      for (int nt = 0; nt < 4; ++nt)
        P[pbase + (((nt * 2 + lnh) ^ pr7) << 3)] = (__bf16)exp2f(sc[nt][rg]);
    }
    bf16x8 pF0 = *(const bf16x8*)&Ps[(wave * 16 + ln) * 64 + s0k];
    bf16x8 pF1 = *(const bf16x8*)&Ps[(wave * 16 + ln) * 64 + s1k];
    ls = __builtin_amdgcn_mfma_f32_16x16x32_bf16(pF0, onesF, ls, 0, 0, 0);
    ls = __builtin_amdgcn_mfma_f32_16x16x32_bf16(pF1, onesF, ls, 0, 0, 0);
#pragma unroll
    for (int dt = 0; dt < 4; ++dt) {
      bf16x8 vF0 = *(const bf16x8*)&Vs[(dt * 16 + ln) * 64 + s0k];
      bf16x8 vF1 = *(const bf16x8*)&Vs[(dt * 16 + ln) * 64 + s1k];
      o[dt] = __builtin_amdgcn_mfma_f32_16x16x32_bf16(pF0, vF0, o[dt], 0, 0, 0);
      o[dt] = __builtin_amdgcn_mfma_f32_16x16x32_bf16(pF1, vF1, o[dt], 0, 0, 0);
    }
  }

  if (gid >= 1536 || !multi) {  // local + single-part global: direct write
#pragma unroll
    for (int dt = 0; dt < 4; ++dt)
#pragma unroll
      for (int rg = 0; rg < 4; ++rg) {
        int row = b * SQ + qb0 + wave * 16 + quad * 4 + rg;
        int e = h * 64 + dt * 16 + ln;
        AOut[(size_t)row * 768 + e] = bfbits(o[dt][rg] / ls[rg]);
      }
  } else {  // multi-part global: partials (slot == gid)
#pragma unroll
    for (int dt = 0; dt < 4; ++dt)
#pragma unroll
      for (int rg = 0; rg < 4; ++rg) {
        int row = wave * 16 + quad * 4 + rg;
        Opart[(size_t)gid * 4096 + row * 64 + dt * 16 + ln] = bfbits(o[dt][rg]);
      }
    if (ln == 0) {
#pragma unroll
      for (int rg = 0; rg < 4; ++rg)
        Lpart[(size_t)gid * 64 + wave * 16 + quad * 4 + rg] = ls[rg];
    }
  }
}

// ---------------- combine split-K partials (global heads, qb>=4) -----------
__global__ __launch_bounds__(256) void combine_parts(
    const unsigned short* __restrict__ Opart, const float* __restrict__ Lpart,
    unsigned short* __restrict__ AOut) {
  const int bid = blockIdx.x;        // 448 = 16 bh * 28 (qb 4..31)
  const int bh = bid / 28, qb = bid % 28 + 4;
  const int b = bh >> 2, h = 8 + (bh & 3);
  int C, np;
  if (qb < 12)      { C = 2 * qb - 4;  np = 2; }
  else if (qb < 20) { C = 3 * qb - 16; np = 3; }
  else if (qb < 28) { C = 4 * qb - 36; np = 4; }
  else              { C = 5 * qb - 64; np = 5; }
  const int slot0 = bh * 96 + C;
  const int t = threadIdx.x, r = t >> 2, c0 = (t & 3) * 16;
  float acc[16];
#pragma unroll
  for (int z = 0; z < 16; ++z) acc[z] = 0.f;
  float l = 0.f;
  for (int p = 0; p < np; ++p) {
    const unsigned short* src = &Opart[(size_t)(slot0 + p) * 4096 + r * 64 + c0];
    bf16x8 v0 = *(const bf16x8*)&src[0];
    bf16x8 v1 = *(const bf16x8*)&src[8];
#pragma unroll
    for (int z = 0; z < 8; ++z) { acc[z] += (float)v0[z]; acc[8 + z] += (float)v1[z]; }
    l += Lpart[(size_t)(slot0 + p) * 64 + r];
  }
  float inv = 1.f / l;
  unsigned short pk[16];
#pragma unroll
  for (int z = 0; z < 16; ++z) pk[z] = bfbits(acc[z] * inv);
  size_t dst = (size_t)(b * SQ + qb * 64 + r) * 768 + h * 64 + c0;
  *(uint4*)&AOut[dst]     = *(uint4*)&pk[0];
  *(uint4*)&AOut[dst + 8] = *(uint4*)&pk[8];
}

// ---------------- launch ----------------
extern "C" void kernel_launch(void* const* d_in, const int* in_sizes, int n_in,
                              void* d_out, int out_size, void* d_ws, size_t ws_size,
                              hipStream_t stream) {
  const float* x      = (const float*)d_in[0];
  const float* w_attn = (const float*)d_in[1];
  const float* b_attn = (const float*)d_in[2];
  const float* w_proj = (const float*)d_in[3];
  const float* b_proj = (const float*)d_in[4];
  float* out = (float*)d_out;

  char* ws = (char*)d_ws;
  size_t off = 0;
  auto alloc = [&](size_t bytes) {
    void* p = ws + off;
    off += (bytes + 255) & ~(size_t)255;
    return p;
  };
  unsigned short* xb     = (unsigned short*)alloc((size_t)8192 * 768 * 2);   // reused as attn buf
  unsigned short* wattnT = (unsigned short*)alloc((size_t)2304 * 768 * 2);
  unsigned short* wprojT = (unsigned short*)alloc((size_t)768 * 768 * 2);
  unsigned short* qkvb   = (unsigned short*)alloc((size_t)8192 * 2304 * 2);
  unsigned short* Vtb    = (unsigned short*)alloc((size_t)48 * 64 * 2048 * 2);
  unsigned short* Kgb    = (unsigned short*)alloc((size_t)16 * 256 * 64 * 2);
  unsigned short* VgTb   = (unsigned short*)alloc((size_t)16 * 64 * 256 * 2);
  int* gidxb             = (int*)alloc((size_t)256 * 4);
  unsigned short* Opartb = (unsigned short*)alloc((size_t)1536 * 4096 * 2);
  float* Lpartb          = (float*)alloc((size_t)1536 * 64 * 4);
  unsigned short* attnb  = xb;  // xb dead after qkv_gemm

  prep<<<dim3(512 + 72 * 24 + 24 * 24), dim3(256), 0, stream>>>(
      x, xb, w_attn, wattnT, w_proj, wprojT);
  qkv_gemm256<<<dim3(288), dim3(512), 0, stream>>>(xb, wattnT, b_attn, qkvb);
  vprep<<<dim3(1536 + 128), dim3(256), 0, stream>>>(qkvb, Vtb, Kgb, VgTb, gidxb);
  attn_kernel<<<dim3(2560), dim3(256), 0, stream>>>(qkvb, Vtb, Kgb, VgTb, gidxb,
                                                    attnb, Opartb, Lpartb);
  combine_parts<<<dim3(448), dim3(256), 0, stream>>>(Opartb, Lpartb, attnb);
  proj_gemm<<<dim3(384), dim3(256), 0, stream>>>(attnb, wprojT, b_proj, out);
}

// Round 6
// 208.980 us; speedup vs baseline: 1.0459x; 1.0459x over previous
//
#include <hip/hip_runtime.h>
#include <stdint.h>

// SparseAttention MI355X bf16-MFMA pipeline. Output f32.
// R17: GEMMs = 128x128 tiles (1152/384 blocks: fine-grained, balanced vs
// R16's 288x256^2 whose 2-round tail idled 87% of CUs half the time) with a
// counted-vmcnt double-buffered K-loop (T3/T4 mechanism, m218):
//   per K-tile: issue 8 next-tile global_load_lds FIRST -> s_waitcnt
//   vmcnt(8) (tile-t landed, t+1's 8 stay in flight; NEVER drain to 0) ->
//   raw s_barrier (NOT __syncthreads: that auto-emits the vmcnt(0) drain
//   that caps the m97 structure) -> 32 MFMA -> lgkmcnt(0)+sched_barrier
//   -> s_barrier (protects buffer overwrite). Dummy stage at last tile
//   keeps vmcnt arithmetic uniform. LDS 64KB dbuf -> 2 blocks/CU.
//   16B-slot XOR swizzle (verified 0-conflict in R16): LDS[r][s] holds
//   global slot s^(r&7); read slot = (kh*4+quad)^(ln&7).
// launch_bounds(256,2): generous reg budget (spill-ladder lesson R2-R4).
// attn unchanged from R15 (52.4us, VGPR 64, no spill, conflicts 0).
// MFMA 16x16x32 bf16 layouts (HW-verified): A[m=lane&15][k=quad*8+j],
// B[k=quad*8+j][n=lane&15], C/D col=lane&15 row=quad*4+reg.

#define NH 12
#define SQ 2048

typedef __bf16 bf16x8 __attribute__((ext_vector_type(8)));
typedef float f32x4 __attribute__((ext_vector_type(4)));

#define GLOAD_LDS16(g, l)                                                      \
  __builtin_amdgcn_global_load_lds(                                            \
      (__attribute__((address_space(1))) void*)(g),                            \
      (__attribute__((address_space(3))) void*)(l), 16, 0, 0)

__device__ __forceinline__ unsigned short bfbits(float f) {
  __bf16 h = (__bf16)f;
  return *(unsigned short*)&h;
}

// ---------------- prep: x->bf16 + both weight transposes (1 kernel) --------
__global__ __launch_bounds__(256) void prep(
    const float* __restrict__ x, unsigned short* __restrict__ xb,
    const float* __restrict__ w_attn, unsigned short* __restrict__ wattnT,
    const float* __restrict__ w_proj, unsigned short* __restrict__ wprojT) {
  const int bid = blockIdx.x, t = threadIdx.x;
  if (bid < 512) {                 // convert x: 8192*768 floats
    const int n4 = 8192 * 768 / 4;
    for (int i = bid * 256 + t; i < n4; i += 512 * 256) {
      float4 v = ((const float4*)x)[i];
      ((ushort4*)xb)[i] = make_ushort4(bfbits(v.x), bfbits(v.y), bfbits(v.z), bfbits(v.w));
    }
    return;
  }
  __shared__ float tile[32][33];
  const float* in; unsigned short* out; int K, N, tl;
  if (bid < 512 + 72 * 24) { in = w_attn; out = wattnT; K = 768; N = 2304; tl = bid - 512; }
  else                     { in = w_proj; out = wprojT; K = 768; N = 768;  tl = bid - 512 - 72 * 24; }
  const int tpr = N / 32;
  const int n0 = (tl % tpr) * 32, k0 = (tl / tpr) * 32;
  const int tx = t & 31, ty = t >> 5;
  for (int r = ty; r < 32; r += 8) tile[r][tx] = in[(size_t)(k0 + r) * N + n0 + tx];
  __syncthreads();
  for (int r = ty; r < 32; r += 8) out[(size_t)(n0 + r) * K + k0 + tx] = bfbits(tile[tx][r]);
}

// ---------------- vprep: V transpose + gcol gather (1 kernel) ----------------
__global__ __launch_bounds__(256) void vprep(const unsigned short* __restrict__ QKV,
                                             unsigned short* __restrict__ Vtb,
                                             unsigned short* __restrict__ Kg,
                                             unsigned short* __restrict__ VgT,
                                             int* __restrict__ gidx) {
  const int id = blockIdx.x, t = threadIdx.x;
  if (id < 1536) {                 // vtrans
    const int bh = id >> 5, b = bh / NH, h = bh % NH;
    const int s0 = (id & 31) * 64;
    __shared__ unsigned short T[64][72];
    const int r = t >> 2, c0 = (t & 3) * 16;
    const size_t src = (size_t)(b * SQ + s0 + r) * 2304 + 1536 + h * 64 + c0;
    *(uint4*)&T[r][c0]     = *(const uint4*)&QKV[src];
    *(uint4*)&T[r][c0 + 8] = *(const uint4*)&QKV[src + 8];
    __syncthreads();
    unsigned short pk[16];
#pragma unroll
    for (int z = 0; z < 16; ++z) pk[z] = T[c0 + z][r];
    size_t dst = (size_t)bh * 131072 + (size_t)r * 2048 + s0 + c0;
    *(uint4*)&Vtb[dst]     = *(uint4*)&pk[0];
    *(uint4*)&Vtb[dst + 8] = *(uint4*)&pk[8];
    return;
  }
  const int g = id - 1536;         // gather: 16 bh * 8 chunks
  const int bh = g >> 3, y = g & 7;
  const int b = bh >> 2, h = 8 + (bh & 3);
  if (g == 0) {
    int c = t;
    gidx[c] = (c < 203) ? (int)((double)c * (2047.0 / 203.0)) : ((c == 203) ? 2047 : -1);
  }
  {  // Kg rows from qkvb K-section
    int c = t, ch = y;
    int col = (c < 203) ? (int)((double)c * (2047.0 / 203.0)) : ((c == 203) ? 2047 : -1);
    uint4 v = {0u, 0u, 0u, 0u};
    if (col >= 0) v = *(const uint4*)&QKV[(size_t)(b * SQ + col) * 2304 + 768 + h * 64 + ch * 8];
    *(uint4*)&Kg[((size_t)bh * 256 + c) * 64 + ch * 8] = v;
  }
  {  // VgT directly from qkvb V-section (transpose gather)
    int d = t >> 2;
    int cb = (t & 3) * 64 + y * 8;
    for (int cc = 0; cc < 8; ++cc) {
      int c = cb + cc;
      int col = (c < 203) ? (int)((double)c * (2047.0 / 203.0)) : ((c == 203) ? 2047 : -1);
      unsigned short v = 0;
      if (col >= 0) v = QKV[(size_t)(b * SQ + col) * 2304 + 1536 + h * 64 + d];
      VgT[((size_t)bh * 64 + d) * 256 + c] = v;
    }
  }
}

// ---- R17 GEMM mainloop: 128x128, BK=64, dbuf, counted vmcnt, raw barriers --
// As/Bs: [2][128][64] u16 (row = 128B = 8 x 16B slots, swz: LDS[r][s] holds
// global slot s^(r&7)). 4 waves (2m x 2n), 32 MFMA/wave/K-tile.
__device__ __forceinline__ void gemm_mainloop(
    const unsigned short* __restrict__ A, const unsigned short* __restrict__ BT,
    int m0, int n0, int tid,
    unsigned short* As, unsigned short* Bs,    // each 2*128*64 u16
    f32x4 acc[4][4]) {
  const int lane = tid & 63, wave = tid >> 6;
  const int wm = wave >> 1, wn = wave & 1;
  const int ln = lane & 15, quad = lane >> 4, ln7 = lane & 7;
  const int srow = tid >> 3;                        // 0..31 (+rr*32)
  const int scol = ((tid & 7) ^ (srow & 7)) * 8;    // pre-swizzled source slot
  const int sbase = wave * 512;                     // u16; lane adds lane*8

#pragma unroll
  for (int mi = 0; mi < 4; ++mi)
#pragma unroll
    for (int ni = 0; ni < 4; ++ni) acc[mi][ni] = (f32x4){0.f, 0.f, 0.f, 0.f};

  auto stage = [&](int kt, int buf) {
    const int k0 = kt * 64;
    const int bo = buf * 8192;
#pragma unroll
    for (int rr = 0; rr < 4; ++rr) {
      GLOAD_LDS16(A  + (size_t)(m0 + rr * 32 + srow) * 768 + k0 + scol,
                  &As[bo + rr * 2048 + sbase]);
      GLOAD_LDS16(BT + (size_t)(n0 + rr * 32 + srow) * 768 + k0 + scol,
                  &Bs[bo + rr * 2048 + sbase]);
    }
  };

  stage(0, 0);
  int buf = 0;
  for (int kt = 0; kt < 12; ++kt) {
    // issue next tile's 8 loads first (dummy re-stage at kt=11 keeps the
    // vmcnt count uniform; writes the dead buffer, data never consumed)
    stage(kt < 11 ? kt + 1 : 11, buf ^ 1);
    asm volatile("s_waitcnt vmcnt(8)" ::: "memory");  // tile-t landed; 8 in flight
    __builtin_amdgcn_sched_barrier(0);
    __builtin_amdgcn_s_barrier();                     // publish staged tile
    __builtin_amdgcn_s_setprio(1);
    const int bo = buf * 8192;
#pragma unroll
    for (int kh = 0; kh < 2; ++kh) {
      const int sk = ((kh * 4 + quad) ^ ln7) * 8;
      bf16x8 aF[4], bF[4];
#pragma unroll
      for (int mi = 0; mi < 4; ++mi)
        aF[mi] = *(const bf16x8*)&As[bo + (wm * 64 + mi * 16 + ln) * 64 + sk];
#pragma unroll
      for (int ni = 0; ni < 4; ++ni)
        bF[ni] = *(const bf16x8*)&Bs[bo + (wn * 64 + ni * 16 + ln) * 64 + sk];
#pragma unroll
      for (int mi = 0; mi < 4; ++mi)
#pragma unroll
        for (int ni = 0; ni < 4; ++ni)
          acc[mi][ni] = __builtin_amdgcn_mfma_f32_16x16x32_bf16(aF[mi], bF[ni], acc[mi][ni], 0, 0, 0);
    }
    __builtin_amdgcn_s_setprio(0);
    asm volatile("s_waitcnt lgkmcnt(0)" ::: "memory"); // all LDS reads done
    __builtin_amdgcn_sched_barrier(0);
    __builtin_amdgcn_s_barrier();                      // safe to overwrite buf
    buf ^= 1;
  }
}

// ---------------- QKV GEMM: row-major bf16 out (XCD-swizzled 1D grid) ------
__global__ __launch_bounds__(256, 2) void qkv_gemm(
    const unsigned short* __restrict__ Xb, const unsigned short* __restrict__ WT,
    const float* __restrict__ bias, unsigned short* __restrict__ Out) {
  __shared__ __attribute__((aligned(16))) unsigned short As[2 * 128 * 64];
  __shared__ __attribute__((aligned(16))) unsigned short Bs[2 * 128 * 64];
  f32x4 acc[4][4];
  // 1152 blocks (64 m x 18 n), 1152%8==0: chunked bijective XCD swizzle.
  const int wg = (blockIdx.x & 7) * 144 + (blockIdx.x >> 3);
  const int m0 = (wg / 18) * 128, n0 = (wg % 18) * 128;
  const int tid = threadIdx.x;
  gemm_mainloop(Xb, WT, m0, n0, tid, As, Bs, acc);
  const int lane = tid & 63, wave = tid >> 6;
  const int wm = wave >> 1, wn = wave & 1, ln = lane & 15, quad = lane >> 4;
#pragma unroll
  for (int mi = 0; mi < 4; ++mi)
#pragma unroll
    for (int ni = 0; ni < 4; ++ni) {
      int n = n0 + wn * 64 + ni * 16 + ln;
      float bs = bias[n];
#pragma unroll
      for (int rg = 0; rg < 4; ++rg) {
        int m = m0 + wm * 64 + mi * 16 + quad * 4 + rg;
        Out[(size_t)m * 2304 + n] = bfbits(acc[mi][ni][rg] + bs);
      }
    }
}

// ---------------- Proj GEMM: fp32 out (XCD-swizzled 1D grid) ---------------
__global__ __launch_bounds__(256, 2) void proj_gemm(
    const unsigned short* __restrict__ Ab, const unsigned short* __restrict__ WT,
    const float* __restrict__ bias, float* __restrict__ Out) {
  __shared__ __attribute__((aligned(16))) unsigned short As[2 * 128 * 64];
  __shared__ __attribute__((aligned(16))) unsigned short Bs[2 * 128 * 64];
  f32x4 acc[4][4];
  // 384 blocks (64 m x 6 n), 384%8==0.
  const int wg = (blockIdx.x & 7) * 48 + (blockIdx.x >> 3);
  const int m0 = (wg / 6) * 128, n0 = (wg % 6) * 128;
  const int tid = threadIdx.x;
  gemm_mainloop(Ab, WT, m0, n0, tid, As, Bs, acc);
  const int lane = tid & 63, wave = tid >> 6;
  const int wm = wave >> 1, wn = wave & 1, ln = lane & 15, quad = lane >> 4;
#pragma unroll
  for (int mi = 0; mi < 4; ++mi)
#pragma unroll
    for (int ni = 0; ni < 4; ++ni)
#pragma unroll
      for (int rg = 0; rg < 4; ++rg) {
        int m = m0 + wm * 64 + mi * 16 + quad * 4 + rg;
        int n = n0 + wn * 64 + ni * 16 + ln;
        Out[(size_t)m * 768 + n] = acc[mi][ni][rg] + bias[n];
      }
}

// ---------------- Flash attention (R15: swizzled LDS, 128-reg budget) ------
// Virtual tile space per (bh,qb) global row: vt 0..3 = g-tiles, vt>=4 ->
// causal kb=vt-4 (0..qb). T=qb+5 tiles split into ceil(T/8) parts of <=8.
// Grid 2560: [0,1536) global parts (slot==gid), [1536,2560) local (<=5 tiles).
// LDS rows are 64 u16 (128B) with 16B-slot XOR swizzle: slot ^= (row&7).
__global__ __launch_bounds__(256, 4) void attn_kernel(
    const unsigned short* __restrict__ QKV,   // [8192][2304]
    const unsigned short* __restrict__ Vtb,   // [48][64][2048]
    const unsigned short* __restrict__ Kg, const unsigned short* __restrict__ VgT,
    const int* __restrict__ gidx,
    unsigned short* __restrict__ AOut,        // [8192][768]
    unsigned short* __restrict__ Opart,       // [1536][4096] bf16
    float* __restrict__ Lpart) {              // [1536][64]
  __shared__ __attribute__((aligned(16))) unsigned short Ks[64 * 64];
  __shared__ __attribute__((aligned(16))) unsigned short Vs[64 * 64];
  __shared__ __attribute__((aligned(16))) unsigned short Ps[64 * 64];  // wave-private rows

  const int gid = blockIdx.x;
  int b, h, qb, vt0, vt1;
  bool multi = false;
  if (gid < 1536) {
    int bh = gid / 96, rem = gid % 96;
    b = bh >> 2; h = 8 + (bh & 3);
    int part;
    if (rem < 4)       { qb = rem;                               part = 0; }
    else if (rem < 20) { int z = rem - 4;  qb = 4 + (z >> 1);    part = z & 1; }
    else if (rem < 44) { int z = rem - 20; int q = z / 3; qb = 12 + q; part = z - 3 * q; }
    else if (rem < 76) { int z = rem - 44; qb = 20 + (z >> 2);   part = z & 3; }
    else               { int z = rem - 76; int q = z / 5; qb = 28 + q; part = z - 5 * q; }
    vt0 = part * 8;
    vt1 = min(vt0 + 8, qb + 5);
    multi = (qb >= 4);
  } else {
    int lid = gid - 1536;
    int bh = lid >> 5; b = bh >> 3; h = bh & 7; qb = lid & 31;
    vt0 = ((qb > 4) ? qb - 4 : 0) + 4;
    vt1 = qb + 5;
  }
  const int qb0 = qb * 64;
  const bool is_local = (h < 8);
  const int tid = threadIdx.x, lane = tid & 63, wave = tid >> 6;
  const int ln = lane & 15, quad = lane >> 4;
  const int bh48 = b * NH + h;
  const int bhg = (b << 2) | (h & 3);

  const size_t qoff = (size_t)(b * SQ + qb0 + wave * 16 + ln) * 2304 + h * 64;
  bf16x8 qA0 = *(const bf16x8*)&QKV[qoff + quad * 8];
  bf16x8 qA1 = *(const bf16x8*)&QKV[qoff + 32 + quad * 8];

  bf16x8 onesF;
#pragma unroll
  for (int z = 0; z < 8; ++z) onesF[z] = (__bf16)1.0f;

  f32x4 o[4];
  f32x4 ls = (f32x4){0.f, 0.f, 0.f, 0.f};
#pragma unroll
  for (int dt = 0; dt < 4; ++dt) o[dt] = (f32x4){0.f, 0.f, 0.f, 0.f};

  const int irow = qb0 + wave * 16 + quad * 4;  // + rg
  const int iw = qb0 + wave * 16;
  const int sr = tid >> 3, sch = tid & 7;
  // swizzled 16B-slot offsets (u16 units)
  const int ssw = (sch ^ (sr & 7)) * 8;             // staging write slot
  const int s0k = (quad ^ (ln & 7)) * 8;            // frag read slot, cols 0..31
  const int s1k = ((quad + 4) ^ (ln & 7)) * 8;      // frag read slot, cols 32..63
  const int lnh = ln >> 3, ln7 = ln & 7;

  // exp2-folded softmax constants: p = exp2(c*S2 - B2) == exp(c/8 - 8)
  const float S2 = 0.125f * 1.44269504f, B2 = 8.0f * 1.44269504f;

  // T14 prefetch registers: next tile's K/V (16 VGPRs)
  uint4 pk0, pk1, pv0, pv1;
  auto issue_load = [&](int vt) {
    if (vt >= 4) {
      const int kstart = (vt - 4) * 64;
      const size_t ko = (size_t)(b * SQ + kstart + sr) * 2304 + 768 + h * 64 + sch * 8;
      pk0 = *(const uint4*)&QKV[ko];
      pk1 = *(const uint4*)&QKV[ko + (size_t)32 * 2304];
      const size_t vo = (size_t)bh48 * 131072 + (size_t)sr * 2048 + kstart + sch * 8;
      pv0 = *(const uint4*)&Vtb[vo];
      pv1 = *(const uint4*)&Vtb[vo + 32 * 2048];
    } else {
      const int kg0 = vt * 64;
      pk0 = *(const uint4*)&Kg[((size_t)bhg * 256 + kg0 + sr) * 64 + sch * 8];
      pk1 = *(const uint4*)&Kg[((size_t)bhg * 256 + kg0 + 32 + sr) * 64 + sch * 8];
      pv0 = *(const uint4*)&VgT[((size_t)bhg * 64 + sr) * 256 + kg0 + sch * 8];
      pv1 = *(const uint4*)&VgT[((size_t)bhg * 64 + 32 + sr) * 256 + kg0 + sch * 8];
    }
  };
  issue_load(vt0);

  for (int vt = vt0; vt < vt1; ++vt) {
    const bool gph = (vt < 4);
    __syncthreads();  // barrier A: all waves done reading prev Ks/Vs (drains prefetch)
    *(uint4*)&Ks[sr * 64 + ssw]        = pk0;   // (32+sr)&7 == sr&7: same slot
    *(uint4*)&Ks[(32 + sr) * 64 + ssw] = pk1;
    *(uint4*)&Vs[sr * 64 + ssw]        = pv0;
    *(uint4*)&Vs[(32 + sr) * 64 + ssw] = pv1;
    __syncthreads();  // barrier B: staged tile visible
    if (vt + 1 < vt1) issue_load(vt + 1);  // in flight across QK+SM+PV

    const int kstart = (vt - 4) * 64;  // valid when !gph
    const int kg0 = vt * 64;           // valid when gph
    float sc[4][4];
    const bool full = !gph && (kstart + 63 <= iw) && (!is_local || kstart >= iw - 241);
#pragma unroll
    for (int nt = 0; nt < 4; ++nt) {
      bf16x8 kF0 = *(const bf16x8*)&Ks[(nt * 16 + ln) * 64 + s0k];
      bf16x8 kF1 = *(const bf16x8*)&Ks[(nt * 16 + ln) * 64 + s1k];
      f32x4 c = (f32x4){0.f, 0.f, 0.f, 0.f};
      c = __builtin_amdgcn_mfma_f32_16x16x32_bf16(qA0, kF0, c, 0, 0, 0);
      c = __builtin_amdgcn_mfma_f32_16x16x32_bf16(qA1, kF1, c, 0, 0, 0);
      if (full) {
#pragma unroll
        for (int rg = 0; rg < 4; ++rg) sc[nt][rg] = c[rg] * S2 - B2;
      } else if (!gph) {
        int j = kstart + nt * 16 + ln;
#pragma unroll
        for (int rg = 0; rg < 4; ++rg) {
          int i = irow + rg;
          bool ok = is_local ? (j >= i - 256 && j <= i) : (j <= i);
          sc[nt][rg] = ok ? (c[rg] * S2 - B2) : -1e9f;
        }
      } else {
        int jg = gidx[kg0 + nt * 16 + ln];
#pragma unroll
        for (int rg = 0; rg < 4; ++rg) {
          bool ok = jg > (irow + rg);
          sc[nt][rg] = ok ? (c[rg] * S2 - B2) : -1e9f;
        }
      }
    }

    // P in its own buffer: each wave writes+reads only rows wave*16..+15 ->
    // no barrier (same-wave DS ordering), prefetch stays in flight.
    __bf16* P = (__bf16*)Ps;
#pragma unroll
    for (int rg = 0; rg < 4; ++rg) {
      int prow = wave * 16 + quad * 4 + rg;
      int pbase = prow * 64 + ln7;
      int pr7 = prow & 7;
#pragma unroll
      for (int nt = 0; nt < 4; ++nt)
        P[pbase + (((nt * 2 + lnh) ^ pr7) << 3)] = (__bf16)exp2f(sc[nt][rg]);
    }
    bf16x8 pF0 = *(const bf16x8*)&Ps[(wave * 16 + ln) * 64 + s0k];
    bf16x8 pF1 = *(const bf16x8*)&Ps[(wave * 16 + ln) * 64 + s1k];
    ls = __builtin_amdgcn_mfma_f32_16x16x32_bf16(pF0, onesF, ls, 0, 0, 0);
    ls = __builtin_amdgcn_mfma_f32_16x16x32_bf16(pF1, onesF, ls, 0, 0, 0);
#pragma unroll
    for (int dt = 0; dt < 4; ++dt) {
      bf16x8 vF0 = *(const bf16x8*)&Vs[(dt * 16 + ln) * 64 + s0k];
      bf16x8 vF1 = *(const bf16x8*)&Vs[(dt * 16 + ln) * 64 + s1k];
      o[dt] = __builtin_amdgcn_mfma_f32_16x16x32_bf16(pF0, vF0, o[dt], 0, 0, 0);
      o[dt] = __builtin_amdgcn_mfma_f32_16x16x32_bf16(pF1, vF1, o[dt], 0, 0, 0);
    }
  }

  if (gid >= 1536 || !multi) {  // local + single-part global: direct write
#pragma unroll
    for (int dt = 0; dt < 4; ++dt)
#pragma unroll
      for (int rg = 0; rg < 4; ++rg) {
        int row = b * SQ + qb0 + wave * 16 + quad * 4 + rg;
        int e = h * 64 + dt * 16 + ln;
        AOut[(size_t)row * 768 + e] = bfbits(o[dt][rg] / ls[rg]);
      }
  } else {  // multi-part global: partials (slot == gid)
#pragma unroll
    for (int dt = 0; dt < 4; ++dt)
#pragma unroll
      for (int rg = 0; rg < 4; ++rg) {
        int row = wave * 16 + quad * 4 + rg;
        Opart[(size_t)gid * 4096 + row * 64 + dt * 16 + ln] = bfbits(o[dt][rg]);
      }
    if (ln == 0) {
#pragma unroll
      for (int rg = 0; rg < 4; ++rg)
        Lpart[(size_t)gid * 64 + wave * 16 + quad * 4 + rg] = ls[rg];
    }
  }
}

// ---------------- combine split-K partials (global heads, qb>=4) -----------
__global__ __launch_bounds__(256) void combine_parts(
    const unsigned short* __restrict__ Opart, const float* __restrict__ Lpart,
    unsigned short* __restrict__ AOut) {
  const int bid = blockIdx.x;        // 448 = 16 bh * 28 (qb 4..31)
  const int bh = bid / 28, qb = bid % 28 + 4;
  const int b = bh >> 2, h = 8 + (bh & 3);
  int C, np;
  if (qb < 12)      { C = 2 * qb - 4;  np = 2; }
  else if (qb < 20) { C = 3 * qb - 16; np = 3; }
  else if (qb < 28) { C = 4 * qb - 36; np = 4; }
  else              { C = 5 * qb - 64; np = 5; }
  const int slot0 = bh * 96 + C;
  const int t = threadIdx.x, r = t >> 2, c0 = (t & 3) * 16;
  float acc[16];
#pragma unroll
  for (int z = 0; z < 16; ++z) acc[z] = 0.f;
  float l = 0.f;
  for (int p = 0; p < np; ++p) {
    const unsigned short* src = &Opart[(size_t)(slot0 + p) * 4096 + r * 64 + c0];
    bf16x8 v0 = *(const bf16x8*)&src[0];
    bf16x8 v1 = *(const bf16x8*)&src[8];
#pragma unroll
    for (int z = 0; z < 8; ++z) { acc[z] += (float)v0[z]; acc[8 + z] += (float)v1[z]; }
    l += Lpart[(size_t)(slot0 + p) * 64 + r];
  }
  float inv = 1.f / l;
  unsigned short pk[16];
#pragma unroll
  for (int z = 0; z < 16; ++z) pk[z] = bfbits(acc[z] * inv);
  size_t dst = (size_t)(b * SQ + qb * 64 + r) * 768 + h * 64 + c0;
  *(uint4*)&AOut[dst]     = *(uint4*)&pk[0];
  *(uint4*)&AOut[dst + 8] = *(uint4*)&pk[8];
}

// ---------------- launch ----------------
extern "C" void kernel_launch(void* const* d_in, const int* in_sizes, int n_in,
                              void* d_out, int out_size, void* d_ws, size_t ws_size,
                              hipStream_t stream) {
  const float* x      = (const float*)d_in[0];
  const float* w_attn = (const float*)d_in[1];
  const float* b_attn = (const float*)d_in[2];
  const float* w_proj = (const float*)d_in[3];
  const float* b_proj = (const float*)d_in[4];
  float* out = (float*)d_out;

  char* ws = (char*)d_ws;
  size_t off = 0;
  auto alloc = [&](size_t bytes) {
    void* p = ws + off;
    off += (bytes + 255) & ~(size_t)255;
    return p;
  };
  unsigned short* xb     = (unsigned short*)alloc((size_t)8192 * 768 * 2);   // reused as attn buf
  unsigned short* wattnT = (unsigned short*)alloc((size_t)2304 * 768 * 2);
  unsigned short* wprojT = (unsigned short*)alloc((size_t)768 * 768 * 2);
  unsigned short* qkvb   = (unsigned short*)alloc((size_t)8192 * 2304 * 2);
  unsigned short* Vtb    = (unsigned short*)alloc((size_t)48 * 64 * 2048 * 2);
  unsigned short* Kgb    = (unsigned short*)alloc((size_t)16 * 256 * 64 * 2);
  unsigned short* VgTb   = (unsigned short*)alloc((size_t)16 * 64 * 256 * 2);
  int* gidxb             = (int*)alloc((size_t)256 * 4);
  unsigned short* Opartb = (unsigned short*)alloc((size_t)1536 * 4096 * 2);
  float* Lpartb          = (float*)alloc((size_t)1536 * 64 * 4);
  unsigned short* attnb  = xb;  // xb dead after qkv_gemm

  prep<<<dim3(512 + 72 * 24 + 24 * 24), dim3(256), 0, stream>>>(
      x, xb, w_attn, wattnT, w_proj, wprojT);
  qkv_gemm<<<dim3(1152), dim3(256), 0, stream>>>(xb, wattnT, b_attn, qkvb);
  vprep<<<dim3(1536 + 128), dim3(256), 0, stream>>>(qkvb, Vtb, Kgb, VgTb, gidxb);
  attn_kernel<<<dim3(2560), dim3(256), 0, stream>>>(qkvb, Vtb, Kgb, VgTb, gidxb,
                                                    attnb, Opartb, Lpartb);
  combine_parts<<<dim3(448), dim3(256), 0, stream>>>(Opartb, Lpartb, attnb);
  proj_gemm<<<dim3(384), dim3(256), 0, stream>>>(attnb, wprojT, b_proj, out);
}

// Round 7
// 205.287 us; speedup vs baseline: 1.0647x; 1.0180x over previous
//
#include <hip/hip_runtime.h>
#include <stdint.h>

// SparseAttention MI355X bf16-MFMA pipeline. Output f32.
// R18:
//  (a) qkv_gemm V-panels (n0>=1536) write Vtb DIRECTLY from acc regs
//      (transposed: C/D layout row=quad*4+rg=key, col=ln->d; rg pairs are
//      consecutive keys -> 2 packed-u32 stores per frag; lanes jointly
//      cover 32B runs). qkvb V-section never written; vprep vtrans arm
//      deleted (grid 1664->128, gather-only; VgT now gathers from Vtb).
//      Saves ~25MB V round-trip + ~1536 blocks.
//  (b) GEMM mainloop: dummy re-stage at kt=11 removed (was +73MB wasted
//      loads) -> branch vmcnt(8)/vmcnt(0); setprio removed (m190: negative
//      on 4-wave lockstep GEMM).
// R17 (kept): 128x128 dbuf counted-vmcnt loop, raw s_barriers, 16B-slot
// XOR swizzle (0-conflict verified), launch_bounds(256,2).
// attn unchanged from R15 (51us, VGPR 64, no spill, conflicts 0).
// MFMA 16x16x32 bf16 layouts (HW-verified): A[m=lane&15][k=quad*8+j],
// B[k=quad*8+j][n=lane&15], C/D col=lane&15 row=quad*4+reg.

#define NH 12
#define SQ 2048

typedef __bf16 bf16x8 __attribute__((ext_vector_type(8)));
typedef float f32x4 __attribute__((ext_vector_type(4)));

#define GLOAD_LDS16(g, l)                                                      \
  __builtin_amdgcn_global_load_lds(                                            \
      (__attribute__((address_space(1))) void*)(g),                            \
      (__attribute__((address_space(3))) void*)(l), 16, 0, 0)

__device__ __forceinline__ unsigned short bfbits(float f) {
  __bf16 h = (__bf16)f;
  return *(unsigned short*)&h;
}

// ---------------- prep: x->bf16 + both weight transposes (1 kernel) --------
__global__ __launch_bounds__(256) void prep(
    const float* __restrict__ x, unsigned short* __restrict__ xb,
    const float* __restrict__ w_attn, unsigned short* __restrict__ wattnT,
    const float* __restrict__ w_proj, unsigned short* __restrict__ wprojT) {
  const int bid = blockIdx.x, t = threadIdx.x;
  if (bid < 512) {                 // convert x: 8192*768 floats
    const int n4 = 8192 * 768 / 4;
    for (int i = bid * 256 + t; i < n4; i += 512 * 256) {
      float4 v = ((const float4*)x)[i];
      ((ushort4*)xb)[i] = make_ushort4(bfbits(v.x), bfbits(v.y), bfbits(v.z), bfbits(v.w));
    }
    return;
  }
  __shared__ float tile[32][33];
  const float* in; unsigned short* out; int K, N, tl;
  if (bid < 512 + 72 * 24) { in = w_attn; out = wattnT; K = 768; N = 2304; tl = bid - 512; }
  else                     { in = w_proj; out = wprojT; K = 768; N = 768;  tl = bid - 512 - 72 * 24; }
  const int tpr = N / 32;
  const int n0 = (tl % tpr) * 32, k0 = (tl / tpr) * 32;
  const int tx = t & 31, ty = t >> 5;
  for (int r = ty; r < 32; r += 8) tile[r][tx] = in[(size_t)(k0 + r) * N + n0 + tx];
  __syncthreads();
  for (int r = ty; r < 32; r += 8) out[(size_t)(n0 + r) * K + k0 + tx] = bfbits(tile[tx][r]);
}

// ---------------- vprep: gcol gather only (V transpose now in qkv) ---------
__global__ __launch_bounds__(256) void vprep(const unsigned short* __restrict__ QKV,
                                             const unsigned short* __restrict__ Vtb,
                                             unsigned short* __restrict__ Kg,
                                             unsigned short* __restrict__ VgT,
                                             int* __restrict__ gidx) {
  const int g = blockIdx.x, t = threadIdx.x;   // 128 = 16 bh * 8 chunks
  const int bh = g >> 3, y = g & 7;
  const int b = bh >> 2, h = 8 + (bh & 3);
  const int bh48 = b * NH + h;
  if (g == 0) {
    int c = t;
    gidx[c] = (c < 203) ? (int)((double)c * (2047.0 / 203.0)) : ((c == 203) ? 2047 : -1);
  }
  {  // Kg rows from qkvb K-section
    int c = t, ch = y;
    int col = (c < 203) ? (int)((double)c * (2047.0 / 203.0)) : ((c == 203) ? 2047 : -1);
    uint4 v = {0u, 0u, 0u, 0u};
    if (col >= 0) v = *(const uint4*)&QKV[(size_t)(b * SQ + col) * 2304 + 768 + h * 64 + ch * 8];
    *(uint4*)&Kg[((size_t)bh * 256 + c) * 64 + ch * 8] = v;
  }
  {  // VgT gathered from Vtb (written by qkv_gemm V-panels)
    int d = t >> 2;
    int cb = (t & 3) * 64 + y * 8;
    for (int cc = 0; cc < 8; ++cc) {
      int c = cb + cc;
      int col = (c < 203) ? (int)((double)c * (2047.0 / 203.0)) : ((c == 203) ? 2047 : -1);
      unsigned short v = 0;
      if (col >= 0) v = Vtb[(size_t)bh48 * 131072 + (size_t)d * 2048 + col];
      VgT[((size_t)bh * 64 + d) * 256 + c] = v;
    }
  }
}

// ---- GEMM mainloop: 128x128, BK=64, dbuf, counted vmcnt, raw barriers -----
// As/Bs: [2][128][64] u16 (row = 128B = 8 x 16B slots, swz: LDS[r][s] holds
// global slot s^(r&7)). 4 waves (2m x 2n), 32 MFMA/wave/K-tile.
__device__ __forceinline__ void gemm_mainloop(
    const unsigned short* __restrict__ A, const unsigned short* __restrict__ BT,
    int m0, int n0, int tid,
    unsigned short* As, unsigned short* Bs,    // each 2*128*64 u16
    f32x4 acc[4][4]) {
  const int lane = tid & 63, wave = tid >> 6;
  const int wm = wave >> 1, wn = wave & 1;
  const int ln = lane & 15, quad = lane >> 4, ln7 = lane & 7;
  const int srow = tid >> 3;                        // 0..31 (+rr*32)
  const int scol = ((tid & 7) ^ (srow & 7)) * 8;    // pre-swizzled source slot
  const int sbase = wave * 512;                     // u16; lane adds lane*8

#pragma unroll
  for (int mi = 0; mi < 4; ++mi)
#pragma unroll
    for (int ni = 0; ni < 4; ++ni) acc[mi][ni] = (f32x4){0.f, 0.f, 0.f, 0.f};

  auto stage = [&](int kt, int buf) {
    const int k0 = kt * 64;
    const int bo = buf * 8192;
#pragma unroll
    for (int rr = 0; rr < 4; ++rr) {
      GLOAD_LDS16(A  + (size_t)(m0 + rr * 32 + srow) * 768 + k0 + scol,
                  &As[bo + rr * 2048 + sbase]);
      GLOAD_LDS16(BT + (size_t)(n0 + rr * 32 + srow) * 768 + k0 + scol,
                  &Bs[bo + rr * 2048 + sbase]);
    }
  };

  stage(0, 0);
  int buf = 0;
  for (int kt = 0; kt < 12; ++kt) {
    if (kt < 11) {
      stage(kt + 1, buf ^ 1);   // next tile's 8 loads issued first
      asm volatile("s_waitcnt vmcnt(8)" ::: "memory");  // tile-t landed; 8 in flight
    } else {
      asm volatile("s_waitcnt vmcnt(0)" ::: "memory");  // last tile: drain
    }
    __builtin_amdgcn_sched_barrier(0);
    __builtin_amdgcn_s_barrier();                     // publish staged tile
    const int bo = buf * 8192;
#pragma unroll
    for (int kh = 0; kh < 2; ++kh) {
      const int sk = ((kh * 4 + quad) ^ ln7) * 8;
      bf16x8 aF[4], bF[4];
#pragma unroll
      for (int mi = 0; mi < 4; ++mi)
        aF[mi] = *(const bf16x8*)&As[bo + (wm * 64 + mi * 16 + ln) * 64 + sk];
#pragma unroll
      for (int ni = 0; ni < 4; ++ni)
        bF[ni] = *(const bf16x8*)&Bs[bo + (wn * 64 + ni * 16 + ln) * 64 + sk];
#pragma unroll
      for (int mi = 0; mi < 4; ++mi)
#pragma unroll
        for (int ni = 0; ni < 4; ++ni)
          acc[mi][ni] = __builtin_amdgcn_mfma_f32_16x16x32_bf16(aF[mi], bF[ni], acc[mi][ni], 0, 0, 0);
    }
    asm volatile("s_waitcnt lgkmcnt(0)" ::: "memory"); // all LDS reads done
    __builtin_amdgcn_sched_barrier(0);
    __builtin_amdgcn_s_barrier();                      // safe to overwrite buf
    buf ^= 1;
  }
}

// ---------------- QKV GEMM: Q/K -> qkvb row-major; V -> Vtb transposed -----
__global__ __launch_bounds__(256, 2) void qkv_gemm(
    const unsigned short* __restrict__ Xb, const unsigned short* __restrict__ WT,
    const float* __restrict__ bias, unsigned short* __restrict__ Out,
    unsigned short* __restrict__ Vtb) {
  __shared__ __attribute__((aligned(16))) unsigned short As[2 * 128 * 64];
  __shared__ __attribute__((aligned(16))) unsigned short Bs[2 * 128 * 64];
  f32x4 acc[4][4];
  // 1152 blocks (64 m x 18 n), 1152%8==0: chunked bijective XCD swizzle.
  const int wg = (blockIdx.x & 7) * 144 + (blockIdx.x >> 3);
  const int m0 = (wg / 18) * 128, n0 = (wg % 18) * 128;
  const int tid = threadIdx.x;
  gemm_mainloop(Xb, WT, m0, n0, tid, As, Bs, acc);
  const int lane = tid & 63, wave = tid >> 6;
  const int wm = wave >> 1, wn = wave & 1, ln = lane & 15, quad = lane >> 4;
  if (n0 < 1536) {   // Q/K panels: row-major bf16 qkvb
#pragma unroll
    for (int mi = 0; mi < 4; ++mi)
#pragma unroll
      for (int ni = 0; ni < 4; ++ni) {
        int n = n0 + wn * 64 + ni * 16 + ln;
        float bs = bias[n];
#pragma unroll
        for (int rg = 0; rg < 4; ++rg) {
          int m = m0 + wm * 64 + mi * 16 + quad * 4 + rg;
          Out[(size_t)m * 2304 + n] = bfbits(acc[mi][ni][rg] + bs);
        }
      }
  } else {           // V panels: write Vtb[bh48][d][key] directly from acc
    const int bb = m0 >> 11;                 // batch (128 | 2048)
    const int key0 = (m0 & 2047) + wm * 64;  // + mi*16 + quad*4 + rg
#pragma unroll
    for (int ni = 0; ni < 4; ++ni) {
      int e = (n0 - 1536) + wn * 64 + ni * 16 + ln;   // 0..767
      int h = e >> 6, d = e & 63;
      float bs = bias[1536 + e];
      size_t rowb = (size_t)(bb * NH + h) * 131072 + (size_t)d * 2048;
#pragma unroll
      for (int mi = 0; mi < 4; ++mi) {
        int key = key0 + mi * 16 + quad * 4;
        unsigned int w0 = (unsigned int)bfbits(acc[mi][ni][0] + bs) |
                          ((unsigned int)bfbits(acc[mi][ni][1] + bs) << 16);
        unsigned int w1 = (unsigned int)bfbits(acc[mi][ni][2] + bs) |
                          ((unsigned int)bfbits(acc[mi][ni][3] + bs) << 16);
        *(unsigned int*)&Vtb[rowb + key]     = w0;   // keys key..key+1
        *(unsigned int*)&Vtb[rowb + key + 2] = w1;   // keys key+2..key+3
      }
    }
  }
}

// ---------------- Proj GEMM: fp32 out (XCD-swizzled 1D grid) ---------------
__global__ __launch_bounds__(256, 2) void proj_gemm(
    const unsigned short* __restrict__ Ab, const unsigned short* __restrict__ WT,
    const float* __restrict__ bias, float* __restrict__ Out) {
  __shared__ __attribute__((aligned(16))) unsigned short As[2 * 128 * 64];
  __shared__ __attribute__((aligned(16))) unsigned short Bs[2 * 128 * 64];
  f32x4 acc[4][4];
  // 384 blocks (64 m x 6 n), 384%8==0.
  const int wg = (blockIdx.x & 7) * 48 + (blockIdx.x >> 3);
  const int m0 = (wg / 6) * 128, n0 = (wg % 6) * 128;
  const int tid = threadIdx.x;
  gemm_mainloop(Ab, WT, m0, n0, tid, As, Bs, acc);
  const int lane = tid & 63, wave = tid >> 6;
  const int wm = wave >> 1, wn = wave & 1, ln = lane & 15, quad = lane >> 4;
#pragma unroll
  for (int mi = 0; mi < 4; ++mi)
#pragma unroll
    for (int ni = 0; ni < 4; ++ni)
#pragma unroll
      for (int rg = 0; rg < 4; ++rg) {
        int m = m0 + wm * 64 + mi * 16 + quad * 4 + rg;
        int n = n0 + wn * 64 + ni * 16 + ln;
        Out[(size_t)m * 768 + n] = acc[mi][ni][rg] + bias[n];
      }
}

// ---------------- Flash attention (R15: swizzled LDS, 128-reg budget) ------
// Virtual tile space per (bh,qb) global row: vt 0..3 = g-tiles, vt>=4 ->
// causal kb=vt-4 (0..qb). T=qb+5 tiles split into ceil(T/8) parts of <=8.
// Grid 2560: [0,1536) global parts (slot==gid), [1536,2560) local (<=5 tiles).
// LDS rows are 64 u16 (128B) with 16B-slot XOR swizzle: slot ^= (row&7).
__global__ __launch_bounds__(256, 4) void attn_kernel(
    const unsigned short* __restrict__ QKV,   // [8192][2304]
    const unsigned short* __restrict__ Vtb,   // [48][64][2048]
    const unsigned short* __restrict__ Kg, const unsigned short* __restrict__ VgT,
    const int* __restrict__ gidx,
    unsigned short* __restrict__ AOut,        // [8192][768]
    unsigned short* __restrict__ Opart,       // [1536][4096] bf16
    float* __restrict__ Lpart) {              // [1536][64]
  __shared__ __attribute__((aligned(16))) unsigned short Ks[64 * 64];
  __shared__ __attribute__((aligned(16))) unsigned short Vs[64 * 64];
  __shared__ __attribute__((aligned(16))) unsigned short Ps[64 * 64];  // wave-private rows

  const int gid = blockIdx.x;
  int b, h, qb, vt0, vt1;
  bool multi = false;
  if (gid < 1536) {
    int bh = gid / 96, rem = gid % 96;
    b = bh >> 2; h = 8 + (bh & 3);
    int part;
    if (rem < 4)       { qb = rem;                               part = 0; }
    else if (rem < 20) { int z = rem - 4;  qb = 4 + (z >> 1);    part = z & 1; }
    else if (rem < 44) { int z = rem - 20; int q = z / 3; qb = 12 + q; part = z - 3 * q; }
    else if (rem < 76) { int z = rem - 44; qb = 20 + (z >> 2);   part = z & 3; }
    else               { int z = rem - 76; int q = z / 5; qb = 28 + q; part = z - 5 * q; }
    vt0 = part * 8;
    vt1 = min(vt0 + 8, qb + 5);
    multi = (qb >= 4);
  } else {
    int lid = gid - 1536;
    int bh = lid >> 5; b = bh >> 3; h = bh & 7; qb = lid & 31;
    vt0 = ((qb > 4) ? qb - 4 : 0) + 4;
    vt1 = qb + 5;
  }
  const int qb0 = qb * 64;
  const bool is_local = (h < 8);
  const int tid = threadIdx.x, lane = tid & 63, wave = tid >> 6;
  const int ln = lane & 15, quad = lane >> 4;
  const int bh48 = b * NH + h;
  const int bhg = (b << 2) | (h & 3);

  const size_t qoff = (size_t)(b * SQ + qb0 + wave * 16 + ln) * 2304 + h * 64;
  bf16x8 qA0 = *(const bf16x8*)&QKV[qoff + quad * 8];
  bf16x8 qA1 = *(const bf16x8*)&QKV[qoff + 32 + quad * 8];

  bf16x8 onesF;
#pragma unroll
  for (int z = 0; z < 8; ++z) onesF[z] = (__bf16)1.0f;

  f32x4 o[4];
  f32x4 ls = (f32x4){0.f, 0.f, 0.f, 0.f};
#pragma unroll
  for (int dt = 0; dt < 4; ++dt) o[dt] = (f32x4){0.f, 0.f, 0.f, 0.f};

  const int irow = qb0 + wave * 16 + quad * 4;  // + rg
  const int iw = qb0 + wave * 16;
  const int sr = tid >> 3, sch = tid & 7;
  // swizzled 16B-slot offsets (u16 units)
  const int ssw = (sch ^ (sr & 7)) * 8;             // staging write slot
  const int s0k = (quad ^ (ln & 7)) * 8;            // frag read slot, cols 0..31
  const int s1k = ((quad + 4) ^ (ln & 7)) * 8;      // frag read slot, cols 32..63
  const int lnh = ln >> 3, ln7 = ln & 7;

  // exp2-folded softmax constants: p = exp2(c*S2 - B2) == exp(c/8 - 8)
  const float S2 = 0.125f * 1.44269504f, B2 = 8.0f * 1.44269504f;

  // T14 prefetch registers: next tile's K/V (16 VGPRs)
  uint4 pk0, pk1, pv0, pv1;
  auto issue_load = [&](int vt) {
    if (vt >= 4) {
      const int kstart = (vt - 4) * 64;
      const size_t ko = (size_t)(b * SQ + kstart + sr) * 2304 + 768 + h * 64 + sch * 8;
      pk0 = *(const uint4*)&QKV[ko];
      pk1 = *(const uint4*)&QKV[ko + (size_t)32 * 2304];
      const size_t vo = (size_t)bh48 * 131072 + (size_t)sr * 2048 + kstart + sch * 8;
      pv0 = *(const uint4*)&Vtb[vo];
      pv1 = *(const uint4*)&Vtb[vo + 32 * 2048];
    } else {
      const int kg0 = vt * 64;
      pk0 = *(const uint4*)&Kg[((size_t)bhg * 256 + kg0 + sr) * 64 + sch * 8];
      pk1 = *(const uint4*)&Kg[((size_t)bhg * 256 + kg0 + 32 + sr) * 64 + sch * 8];
      pv0 = *(const uint4*)&VgT[((size_t)bhg * 64 + sr) * 256 + kg0 + sch * 8];
      pv1 = *(const uint4*)&VgT[((size_t)bhg * 64 + 32 + sr) * 256 + kg0 + sch * 8];
    }
  };
  issue_load(vt0);

  for (int vt = vt0; vt < vt1; ++vt) {
    const bool gph = (vt < 4);
    __syncthreads();  // barrier A: all waves done reading prev Ks/Vs (drains prefetch)
    *(uint4*)&Ks[sr * 64 + ssw]        = pk0;   // (32+sr)&7 == sr&7: same slot
    *(uint4*)&Ks[(32 + sr) * 64 + ssw] = pk1;
    *(uint4*)&Vs[sr * 64 + ssw]        = pv0;
    *(uint4*)&Vs[(32 + sr) * 64 + ssw] = pv1;
    __syncthreads();  // barrier B: staged tile visible
    if (vt + 1 < vt1) issue_load(vt + 1);  // in flight across QK+SM+PV

    const int kstart = (vt - 4) * 64;  // valid when !gph
    const int kg0 = vt * 64;           // valid when gph
    float sc[4][4];
    const bool full = !gph && (kstart + 63 <= iw) && (!is_local || kstart >= iw - 241);
#pragma unroll
    for (int nt = 0; nt < 4; ++nt) {
      bf16x8 kF0 = *(const bf16x8*)&Ks[(nt * 16 + ln) * 64 + s0k];
      bf16x8 kF1 = *(const bf16x8*)&Ks[(nt * 16 + ln) * 64 + s1k];
      f32x4 c = (f32x4){0.f, 0.f, 0.f, 0.f};
      c = __builtin_amdgcn_mfma_f32_16x16x32_bf16(qA0, kF0, c, 0, 0, 0);
      c = __builtin_amdgcn_mfma_f32_16x16x32_bf16(qA1, kF1, c, 0, 0, 0);
      if (full) {
#pragma unroll
        for (int rg = 0; rg < 4; ++rg) sc[nt][rg] = c[rg] * S2 - B2;
      } else if (!gph) {
        int j = kstart + nt * 16 + ln;
#pragma unroll
        for (int rg = 0; rg < 4; ++rg) {
          int i = irow + rg;
          bool ok = is_local ? (j >= i - 256 && j <= i) : (j <= i);
          sc[nt][rg] = ok ? (c[rg] * S2 - B2) : -1e9f;
        }
      } else {
        int jg = gidx[kg0 + nt * 16 + ln];
#pragma unroll
        for (int rg = 0; rg < 4; ++rg) {
          bool ok = jg > (irow + rg);
          sc[nt][rg] = ok ? (c[rg] * S2 - B2) : -1e9f;
        }
      }
    }

    // P in its own buffer: each wave writes+reads only rows wave*16..+15 ->
    // no barrier (same-wave DS ordering), prefetch stays in flight.
    __bf16* P = (__bf16*)Ps;
#pragma unroll
    for (int rg = 0; rg < 4; ++rg) {
      int prow = wave * 16 + quad * 4 + rg;
      int pbase = prow * 64 + ln7;
      int pr7 = prow & 7;
#pragma unroll
      for (int nt = 0; nt < 4; ++nt)
        P[pbase + (((nt * 2 + lnh) ^ pr7) << 3)] = (__bf16)exp2f(sc[nt][rg]);
    }
    bf16x8 pF0 = *(const bf16x8*)&Ps[(wave * 16 + ln) * 64 + s0k];
    bf16x8 pF1 = *(const bf16x8*)&Ps[(wave * 16 + ln) * 64 + s1k];
    ls = __builtin_amdgcn_mfma_f32_16x16x32_bf16(pF0, onesF, ls, 0, 0, 0);
    ls = __builtin_amdgcn_mfma_f32_16x16x32_bf16(pF1, onesF, ls, 0, 0, 0);
#pragma unroll
    for (int dt = 0; dt < 4; ++dt) {
      bf16x8 vF0 = *(const bf16x8*)&Vs[(dt * 16 + ln) * 64 + s0k];
      bf16x8 vF1 = *(const bf16x8*)&Vs[(dt * 16 + ln) * 64 + s1k];
      o[dt] = __builtin_amdgcn_mfma_f32_16x16x32_bf16(pF0, vF0, o[dt], 0, 0, 0);
      o[dt] = __builtin_amdgcn_mfma_f32_16x16x32_bf16(pF1, vF1, o[dt], 0, 0, 0);
    }
  }

  if (gid >= 1536 || !multi) {  // local + single-part global: direct write
#pragma unroll
    for (int dt = 0; dt < 4; ++dt)
#pragma unroll
      for (int rg = 0; rg < 4; ++rg) {
        int row = b * SQ + qb0 + wave * 16 + quad * 4 + rg;
        int e = h * 64 + dt * 16 + ln;
        AOut[(size_t)row * 768 + e] = bfbits(o[dt][rg] / ls[rg]);
      }
  } else {  // multi-part global: partials (slot == gid)
#pragma unroll
    for (int dt = 0; dt < 4; ++dt)
#pragma unroll
      for (int rg = 0; rg < 4; ++rg) {
        int row = wave * 16 + quad * 4 + rg;
        Opart[(size_t)gid * 4096 + row * 64 + dt * 16 + ln] = bfbits(o[dt][rg]);
      }
    if (ln == 0) {
#pragma unroll
      for (int rg = 0; rg < 4; ++rg)
        Lpart[(size_t)gid * 64 + wave * 16 + quad * 4 + rg] = ls[rg];
    }
  }
}

// ---------------- combine split-K partials (global heads, qb>=4) -----------
__global__ __launch_bounds__(256) void combine_parts(
    const unsigned short* __restrict__ Opart, const float* __restrict__ Lpart,
    unsigned short* __restrict__ AOut) {
  const int bid = blockIdx.x;        // 448 = 16 bh * 28 (qb 4..31)
  const int bh = bid / 28, qb = bid % 28 + 4;
  const int b = bh >> 2, h = 8 + (bh & 3);
  int C, np;
  if (qb < 12)      { C = 2 * qb - 4;  np = 2; }
  else if (qb < 20) { C = 3 * qb - 16; np = 3; }
  else if (qb < 28) { C = 4 * qb - 36; np = 4; }
  else              { C = 5 * qb - 64; np = 5; }
  const int slot0 = bh * 96 + C;
  const int t = threadIdx.x, r = t >> 2, c0 = (t & 3) * 16;
  float acc[16];
#pragma unroll
  for (int z = 0; z < 16; ++z) acc[z] = 0.f;
  float l = 0.f;
  for (int p = 0; p < np; ++p) {
    const unsigned short* src = &Opart[(size_t)(slot0 + p) * 4096 + r * 64 + c0];
    bf16x8 v0 = *(const bf16x8*)&src[0];
    bf16x8 v1 = *(const bf16x8*)&src[8];
#pragma unroll
    for (int z = 0; z < 8; ++z) { acc[z] += (float)v0[z]; acc[8 + z] += (float)v1[z]; }
    l += Lpart[(size_t)(slot0 + p) * 64 + r];
  }
  float inv = 1.f / l;
  unsigned short pk[16];
#pragma unroll
  for (int z = 0; z < 16; ++z) pk[z] = bfbits(acc[z] * inv);
  size_t dst = (size_t)(b * SQ + qb * 64 + r) * 768 + h * 64 + c0;
  *(uint4*)&AOut[dst]     = *(uint4*)&pk[0];
  *(uint4*)&AOut[dst + 8] = *(uint4*)&pk[8];
}

// ---------------- launch ----------------
extern "C" void kernel_launch(void* const* d_in, const int* in_sizes, int n_in,
                              void* d_out, int out_size, void* d_ws, size_t ws_size,
                              hipStream_t stream) {
  const float* x      = (const float*)d_in[0];
  const float* w_attn = (const float*)d_in[1];
  const float* b_attn = (const float*)d_in[2];
  const float* w_proj = (const float*)d_in[3];
  const float* b_proj = (const float*)d_in[4];
  float* out = (float*)d_out;

  char* ws = (char*)d_ws;
  size_t off = 0;
  auto alloc = [&](size_t bytes) {
    void* p = ws + off;
    off += (bytes + 255) & ~(size_t)255;
    return p;
  };
  unsigned short* xb     = (unsigned short*)alloc((size_t)8192 * 768 * 2);   // reused as attn buf
  unsigned short* wattnT = (unsigned short*)alloc((size_t)2304 * 768 * 2);
  unsigned short* wprojT = (unsigned short*)alloc((size_t)768 * 768 * 2);
  unsigned short* qkvb   = (unsigned short*)alloc((size_t)8192 * 2304 * 2);
  unsigned short* Vtb    = (unsigned short*)alloc((size_t)48 * 64 * 2048 * 2);
  unsigned short* Kgb    = (unsigned short*)alloc((size_t)16 * 256 * 64 * 2);
  unsigned short* VgTb   = (unsigned short*)alloc((size_t)16 * 64 * 256 * 2);
  int* gidxb             = (int*)alloc((size_t)256 * 4);
  unsigned short* Opartb = (unsigned short*)alloc((size_t)1536 * 4096 * 2);
  float* Lpartb          = (float*)alloc((size_t)1536 * 64 * 4);
  unsigned short* attnb  = xb;  // xb dead after qkv_gemm

  prep<<<dim3(512 + 72 * 24 + 24 * 24), dim3(256), 0, stream>>>(
      x, xb, w_attn, wattnT, w_proj, wprojT);
  qkv_gemm<<<dim3(1152), dim3(256), 0, stream>>>(xb, wattnT, b_attn, qkvb, Vtb);
  vprep<<<dim3(128), dim3(256), 0, stream>>>(qkvb, Vtb, Kgb, VgTb, gidxb);
  attn_kernel<<<dim3(2560), dim3(256), 0, stream>>>(qkvb, Vtb, Kgb, VgTb, gidxb,
                                                    attnb, Opartb, Lpartb);
  combine_parts<<<dim3(448), dim3(256), 0, stream>>>(Opartb, Lpartb, attnb);
  proj_gemm<<<dim3(384), dim3(256), 0, stream>>>(attnb, wprojT, b_proj, out);
}